// Round 1
// baseline (3930.152 us; speedup 1.0000x reference)
//
#include <hip/hip_runtime.h>
#include <float.h>

#define FEAT 512
#define TOPK 5
#define BM 32
#define BN 256
#define BK 32
#define NTILE 5
#define CHUNK (BN * NTILE)  // 1280

// composite order: higher score wins; on equal score, lower index wins (jax.lax.top_k tie rule)
__device__ __forceinline__ bool better(float s1, int i1, float s2, int i2) {
    return (s1 > s2) || (s1 == s2 && i1 < i2);
}

__device__ __forceinline__ void insert5(float (&s)[TOPK], int (&ix)[TOPK], float v, int idx) {
    if (better(v, idx, s[TOPK - 1], ix[TOPK - 1])) {
        s[TOPK - 1] = v; ix[TOPK - 1] = idx;
#pragma unroll
        for (int t = TOPK - 1; t > 0; --t) {
            if (better(s[t], ix[t], s[t - 1], ix[t - 1])) {
                float tf = s[t]; s[t] = s[t - 1]; s[t - 1] = tf;
                int td = ix[t]; ix[t] = ix[t - 1]; ix[t - 1] = td;
            }
        }
    }
}

#define CE(a, b)                                                        \
    {                                                                   \
        if (better(ms[b], mi[b], ms[a], mi[a])) {                       \
            float tf = ms[a]; ms[a] = ms[b]; ms[b] = tf;                \
            int td = mi[a]; mi[a] = mi[b]; mi[b] = td;                  \
        }                                                               \
    }

// merge my sorted-desc top5 with lane^mask's: elementwise max against reversed
// other list (bitonic top-k trick), then 10-CE bubble network re-sort.
__device__ __forceinline__ void merge5(float (&s)[TOPK], int (&ix)[TOPK], int mask) {
    float ms[TOPK]; int mi[TOPK];
#pragma unroll
    for (int j = 0; j < TOPK; ++j) {
        float osv = __shfl_xor(s[TOPK - 1 - j], mask);
        int oiv = __shfl_xor(ix[TOPK - 1 - j], mask);
        if (better(osv, oiv, s[j], ix[j])) { ms[j] = osv; mi[j] = oiv; }
        else { ms[j] = s[j]; mi[j] = ix[j]; }
    }
    // bubble sorting network (guaranteed), 10 CEs
    CE(0, 1) CE(1, 2) CE(2, 3) CE(3, 4)
    CE(0, 1) CE(1, 2) CE(2, 3)
    CE(0, 1) CE(1, 2)
    CE(0, 1)
#pragma unroll
    for (int j = 0; j < TOPK; ++j) { s[j] = ms[j]; ix[j] = mi[j]; }
}

// Kernel 1: inverse L2 norms of attr rows. One wave per row.
__global__ __launch_bounds__(256) void norm_kernel(const float* __restrict__ attr,
                                                   float* __restrict__ inv) {
    const int w = threadIdx.x >> 6;
    const int lane = threadIdx.x & 63;
    const int row = blockIdx.x * 4 + w;
    const float4* a4 = reinterpret_cast<const float4*>(attr) + (size_t)row * (FEAT / 4);
    float4 v0 = a4[lane * 2], v1 = a4[lane * 2 + 1];
    float s = v0.x * v0.x + v0.y * v0.y + v0.z * v0.z + v0.w * v0.w +
              v1.x * v1.x + v1.y * v1.y + v1.z * v1.z + v1.w * v1.w;
#pragma unroll
    for (int m = 1; m < 64; m <<= 1) s += __shfl_xor(s, m);
    if (lane == 0) inv[row] = 1.0f / sqrtf(s);
}

// Kernel 2: fused tiled fp32 GEMM + per-chunk top-5.
// Grid: (batch/BM, nattr/CHUNK). Block 256 threads = 4 waves.
// Thread tile 4 rows x 8 cols (cols split as tx*4..+3 and 128+tx*4..+3 for
// conflict-free linear-sweep ds_read_b128 fragment reads).
__global__ __launch_bounds__(256) void sim_topk_kernel(
    const float* __restrict__ img, const float* __restrict__ attr,
    const float* __restrict__ inv, float* __restrict__ cand_s,
    int* __restrict__ cand_i, int nchunk) {
    __shared__ __align__(16) float As[BK][BM + 4];   // k-major, stride 36 (144B, 16B-aligned)
    __shared__ __align__(16) float Bs[BK][BN + 4];   // k-major, stride 260 (1040B, 16B-aligned)
    const int tid = threadIdx.x;
    const int tx = tid & 31, ty = tid >> 5;
    const int rowbase = blockIdx.x * BM;
    const int chunk = blockIdx.y;
    const int chunkbase = chunk * CHUNK;

    float ts[4][TOPK]; int ti[4][TOPK];
#pragma unroll
    for (int r = 0; r < 4; ++r)
#pragma unroll
        for (int j = 0; j < TOPK; ++j) { ts[r][j] = -FLT_MAX; ti[r][j] = 0x7fffffff; }

    const int lr = tid >> 3;        // 0..31
    const int lk = (tid & 7) * 4;   // 0,4,..,28

    for (int t = 0; t < NTILE; ++t) {
        const int colbase = chunkbase + t * BN;
        float acc[4][8];
#pragma unroll
        for (int r = 0; r < 4; ++r)
#pragma unroll
            for (int e = 0; e < 8; ++e) acc[r][e] = 0.f;

        for (int kb = 0; kb < FEAT; kb += BK) {
            // stage A tile (32 rows x 32 k), transposed into k-major LDS
            {
                const float4 av = *reinterpret_cast<const float4*>(
                    &img[(size_t)(rowbase + lr) * FEAT + kb + lk]);
                As[lk + 0][lr] = av.x; As[lk + 1][lr] = av.y;
                As[lk + 2][lr] = av.z; As[lk + 3][lr] = av.w;
            }
            // stage B tile (256 attrs x 32 k), transposed
#pragma unroll
            for (int p = 0; p < 8; ++p) {
                const int c = lr + p * 32;
                const float4 bv = *reinterpret_cast<const float4*>(
                    &attr[(size_t)(colbase + c) * FEAT + kb + lk]);
                Bs[lk + 0][c] = bv.x; Bs[lk + 1][c] = bv.y;
                Bs[lk + 2][c] = bv.z; Bs[lk + 3][c] = bv.w;
            }
            __syncthreads();
#pragma unroll
            for (int kk = 0; kk < BK; ++kk) {
                const float4 a4 = *reinterpret_cast<const float4*>(&As[kk][ty * 4]);
                const float4 b0 = *reinterpret_cast<const float4*>(&Bs[kk][tx * 4]);
                const float4 b1 = *reinterpret_cast<const float4*>(&Bs[kk][128 + tx * 4]);
                const float ar[4] = {a4.x, a4.y, a4.z, a4.w};
                const float bc[8] = {b0.x, b0.y, b0.z, b0.w, b1.x, b1.y, b1.z, b1.w};
#pragma unroll
                for (int r = 0; r < 4; ++r)
#pragma unroll
                    for (int e = 0; e < 8; ++e)
                        acc[r][e] = fmaf(ar[r], bc[e], acc[r][e]);
            }
            __syncthreads();
        }
        // fold in this BN tile's sims (scaled by attr invnorm) into running top-5
#pragma unroll
        for (int e = 0; e < 8; ++e) {
            const int col = (e < 4) ? (tx * 4 + e) : (128 + tx * 4 + e - 4);
            const int gidx = colbase + col;
            const float sc = inv[gidx];
#pragma unroll
            for (int r = 0; r < 4; ++r)
                insert5(ts[r], ti[r], acc[r][e] * sc, gidx);
        }
    }
    // butterfly merge across the 32 tx lanes (stays within half-wave)
#pragma unroll
    for (int r = 0; r < 4; ++r) {
        merge5(ts[r], ti[r], 1);
        merge5(ts[r], ti[r], 2);
        merge5(ts[r], ti[r], 4);
        merge5(ts[r], ti[r], 8);
        merge5(ts[r], ti[r], 16);
    }
    if (tx == 0) {
#pragma unroll
        for (int r = 0; r < 4; ++r) {
            const int row = rowbase + ty * 4 + r;
#pragma unroll
            for (int j = 0; j < TOPK; ++j) {
                const size_t o = (size_t)row * (nchunk * TOPK) + chunk * TOPK + j;
                cand_s[o] = ts[r][j];
                cand_i[o] = ti[r][j];
            }
        }
    }
}

// Kernel 3: merge 50 chunks x 5 candidates -> final top-5 per row. One wave per row.
__global__ __launch_bounds__(64) void merge_kernel(
    const float* __restrict__ cand_s, const int* __restrict__ cand_i,
    float* __restrict__ out_scores, int* __restrict__ final_i, int ncand) {
    const int row = blockIdx.x;
    const int lane = threadIdx.x;
    float s[TOPK]; int ix[TOPK];
#pragma unroll
    for (int j = 0; j < TOPK; ++j) { s[j] = -FLT_MAX; ix[j] = 0x7fffffff; }
    for (int e = lane; e < ncand; e += 64)
        insert5(s, ix, cand_s[(size_t)row * ncand + e], cand_i[(size_t)row * ncand + e]);
    merge5(s, ix, 1); merge5(s, ix, 2); merge5(s, ix, 4);
    merge5(s, ix, 8); merge5(s, ix, 16); merge5(s, ix, 32);
    if (lane == 0) {
#pragma unroll
        for (int j = 0; j < TOPK; ++j) {
            out_scores[(size_t)row * TOPK + j] = s[j];
            final_i[(size_t)row * TOPK + j] = ix[j];
        }
    }
}

// Kernel 4: gather normalized attr vectors for the winners.
__global__ __launch_bounds__(128) void gather_kernel(
    const float* __restrict__ attr, const float* __restrict__ inv,
    const int* __restrict__ final_i, float* __restrict__ out0) {
    const int pair = blockIdx.x;  // b*TOPK + k
    const int fi = final_i[pair];
    const float sc = inv[fi];
    const float4 v =
        reinterpret_cast<const float4*>(attr)[(size_t)fi * (FEAT / 4) + threadIdx.x];
    float4 o;
    o.x = v.x * sc; o.y = v.y * sc; o.z = v.z * sc; o.w = v.w * sc;
    reinterpret_cast<float4*>(out0)[(size_t)pair * (FEAT / 4) + threadIdx.x] = o;
}

extern "C" void kernel_launch(void* const* d_in, const int* in_sizes, int n_in,
                              void* d_out, int out_size, void* d_ws, size_t ws_size,
                              hipStream_t stream) {
    const float* img = (const float*)d_in[0];
    const float* attr = (const float*)d_in[1];
    const int batch = in_sizes[0] / FEAT;   // 4096
    const int nattr = in_sizes[1] / FEAT;   // 64000
    const int nchunk = nattr / CHUNK;       // 50
    const int ncand = nchunk * TOPK;        // 250

    // workspace layout (all 4B-aligned): ~8.5 MB total
    float* inv = (float*)d_ws;                                   // nattr
    float* cand_s = inv + nattr;                                 // batch*ncand
    int* cand_i = (int*)(cand_s + (size_t)batch * ncand);        // batch*ncand
    int* final_i = cand_i + (size_t)batch * ncand;               // batch*TOPK

    float* out0 = (float*)d_out;                                 // [batch][TOPK][FEAT]
    float* out_scores = out0 + (size_t)batch * TOPK * FEAT;      // [batch][TOPK]

    norm_kernel<<<nattr / 4, 256, 0, stream>>>(attr, inv);
    dim3 g2(batch / BM, nchunk);
    sim_topk_kernel<<<g2, 256, 0, stream>>>(img, attr, inv, cand_s, cand_i, nchunk);
    merge_kernel<<<batch, 64, 0, stream>>>(cand_s, cand_i, out_scores, final_i, ncand);
    gather_kernel<<<batch * TOPK, 128, 0, stream>>>(attr, inv, final_i, out0);
}

// Round 2
// 629.558 us; speedup vs baseline: 6.2427x; 6.2427x over previous
//
#include <hip/hip_runtime.h>
#include <float.h>
#include <stdint.h>

#define FEAT 512
#define TOPK 5
#define BM 128
#define BN 128
#define BK 32
#define NSUB 10
#define CHUNKC (BN * NSUB)   // 1280 cols per block
#define KSTEPS (FEAT / BK)   // 16
#define NSEL 16

typedef __attribute__((ext_vector_type(8))) short bf16x8;
typedef __attribute__((ext_vector_type(8))) unsigned short ushort8;
typedef __attribute__((ext_vector_type(4))) float f32x4;

__device__ __forceinline__ unsigned short f2bf(float f) {
    unsigned x = __float_as_uint(f);
    x += 0x7FFFu + ((x >> 16) & 1u);   // RNE
    return (unsigned short)(x >> 16);
}

__device__ __forceinline__ void gl_lds16(const void* g, void* lds) {
    __builtin_amdgcn_global_load_lds(
        (const __attribute__((address_space(1))) unsigned int*)g,
        (__attribute__((address_space(3))) unsigned int*)lds, 16, 0, 0);
}

// ---------- kernel 1: (optional) L2-normalize + convert fp32 -> bf16 ----------
__global__ __launch_bounds__(256) void convert_kernel(
    const float* __restrict__ in, unsigned short* __restrict__ outB,
    float* __restrict__ inv, int do_norm) {
    const int w = threadIdx.x >> 6, l = threadIdx.x & 63;
    const int row = blockIdx.x * 4 + w;
    const float4* p = reinterpret_cast<const float4*>(in) + (size_t)row * (FEAT / 4);
    const float4 v0 = p[l * 2], v1 = p[l * 2 + 1];
    float sc = 1.0f;
    if (do_norm) {
        float s = v0.x * v0.x + v0.y * v0.y + v0.z * v0.z + v0.w * v0.w +
                  v1.x * v1.x + v1.y * v1.y + v1.z * v1.z + v1.w * v1.w;
#pragma unroll
        for (int m = 1; m < 64; m <<= 1) s += __shfl_xor(s, m);
        sc = 1.0f / sqrtf(s);
        if (l == 0) inv[row] = sc;
    }
    ushort8 o;
    o[0] = f2bf(v0.x * sc); o[1] = f2bf(v0.y * sc);
    o[2] = f2bf(v0.z * sc); o[3] = f2bf(v0.w * sc);
    o[4] = f2bf(v1.x * sc); o[5] = f2bf(v1.y * sc);
    o[6] = f2bf(v1.z * sc); o[7] = f2bf(v1.w * sc);
    *reinterpret_cast<ushort8*>(outB + (size_t)row * FEAT + l * 8) = o;
}

// ---------- kernel 2: bf16 MFMA coarse scoring + fused per-row top-5 ----------
// Grid (batch/128, nchunk). 256 thr = 4 waves (2x2), each wave 64x64 per subtile.
// Per wave: epilogue transposes acc via private LDS strip so lane = row, then
// packed (score_hi21 | (2047-lcol)) running top-5 in 5 VGPRs across 10 subtiles.
__global__ __launch_bounds__(256, 2) void coarse_kernel(
    const unsigned short* __restrict__ imgB,
    const unsigned short* __restrict__ attrB,
    unsigned* __restrict__ cand, int nchunk) {
    __shared__ unsigned short As[BM * BK];   // 8 KB, [row][k] 64B/row (linear for gl_lds)
    __shared__ unsigned short Bs[BN * BK];   // 8 KB, [col][k]
    __shared__ float Ep[4][64 * 20];         // 20 KB, per-wave transpose strip (pad 20)

    const int tid = threadIdx.x;
    const int w = tid >> 6, l = tid & 63;
    const int wr = w >> 1, wc = w & 1;
    const int rowbase = blockIdx.x * BM;
    const int chunk = blockIdx.y;
    const int chunkbase = chunk * CHUNKC;

    // staging: thread t moves two 16B pieces per tile (linear LDS, wave-uniform base)
    const int srow = tid >> 2;               // 0..63
    const int skoff = (tid & 3) * 8;         // ushort offset (16B granule)
    const unsigned short* gA0 = imgB + (size_t)(rowbase + srow) * FEAT + skoff;
    const unsigned short* gA1 = gA0 + (size_t)64 * FEAT;
    unsigned short* dA0 = As + tid * 8;
    unsigned short* dA1 = As + 2048 + tid * 8;
    unsigned short* dB0 = Bs + tid * 8;
    unsigned short* dB1 = Bs + 2048 + tid * 8;

    // fragment addressing: A row = l&15, k-chunk = (l>>4)*8 (16x16x32 bf16 layout)
    const int fr = l & 15;
    const int fk = (l >> 4) * 8;
    const unsigned short* lA0 = As + (wr * 64 + fr) * BK + fk;
    const unsigned short* lB0 = Bs + (wc * 64 + fr) * BK + fk;
    float* ep = &Ep[w][0];

    unsigned tops[TOPK] = {0u, 0u, 0u, 0u, 0u};

    for (int t = 0; t < NSUB; ++t) {
        const int colbase = chunkbase + t * BN;
        const unsigned short* gB0 = attrB + (size_t)(colbase + srow) * FEAT + skoff;
        const unsigned short* gB1 = gB0 + (size_t)64 * FEAT;
        f32x4 acc[4][4];
#pragma unroll
        for (int mf = 0; mf < 4; ++mf)
#pragma unroll
            for (int nf = 0; nf < 4; ++nf) acc[mf][nf] = (f32x4){0.f, 0.f, 0.f, 0.f};

        for (int kb = 0; kb < KSTEPS; ++kb) {
            const int ko = kb * BK;
            gl_lds16(gA0 + ko, dA0);
            gl_lds16(gA1 + ko, dA1);
            gl_lds16(gB0 + ko, dB0);
            gl_lds16(gB1 + ko, dB1);
            __syncthreads();   // compiler drains vmcnt before barrier
            bf16x8 af[4], bfv[4];
#pragma unroll
            for (int mf = 0; mf < 4; ++mf)
                af[mf] = *reinterpret_cast<const bf16x8*>(lA0 + mf * 16 * BK);
#pragma unroll
            for (int nf = 0; nf < 4; ++nf)
                bfv[nf] = *reinterpret_cast<const bf16x8*>(lB0 + nf * 16 * BK);
#pragma unroll
            for (int mf = 0; mf < 4; ++mf)
#pragma unroll
                for (int nf = 0; nf < 4; ++nf)
                    acc[mf][nf] = __builtin_amdgcn_mfma_f32_16x16x32_bf16(
                        af[mf], bfv[nf], acc[mf][nf], 0, 0, 0);
            __syncthreads();
        }

        // epilogue: per 16-col group, scatter C into per-wave strip, read row-major
#pragma unroll
        for (int nf = 0; nf < 4; ++nf) {
#pragma unroll
            for (int mf = 0; mf < 4; ++mf)
#pragma unroll
                for (int r = 0; r < 4; ++r)
                    ep[(mf * 16 + (l >> 4) * 4 + r) * 20 + fr] = acc[mf][nf][r];
            asm volatile("s_waitcnt lgkmcnt(0)" ::: "memory");  // wave-sync LDS RAW
            const int lcolbase = t * BN + wc * 64 + nf * 16;
#pragma unroll
            for (int q = 0; q < 4; ++q) {
                const float4 v = *reinterpret_cast<const float4*>(ep + l * 20 + q * 4);
                const float vv[4] = {v.x, v.y, v.z, v.w};
#pragma unroll
                for (int j = 0; j < 4; ++j) {
                    unsigned u = __float_as_uint(vv[j]);
                    u = ((int)u < 0) ? ~u : (u | 0x80000000u);
                    const unsigned p =
                        (u & 0xFFFFF800u) | (unsigned)(2047 - (lcolbase + q * 4 + j));
                    if (p > tops[4]) {
                        tops[4] = p;
#pragma unroll
                        for (int x = 4; x > 0; --x)
                            if (tops[x] > tops[x - 1]) {
                                const unsigned tmp = tops[x];
                                tops[x] = tops[x - 1]; tops[x - 1] = tmp;
                            }
                    }
                }
            }
            asm volatile("s_waitcnt lgkmcnt(0)" ::: "memory");  // strip reuse (WAR)
        }
    }
    // lane l owns row (rowbase + wr*64 + l), cols [wc half of chunk]
    unsigned* dst =
        cand + ((size_t)(rowbase + wr * 64 + l) * nchunk + chunk) * 10 + wc * 5;
#pragma unroll
    for (int j = 0; j < TOPK; ++j) dst[j] = tops[j];
}

// ---------- kernel 3: per-row merge of 500 packed candidates -> top-16 ----------
__global__ __launch_bounds__(64) void select16_kernel(
    const unsigned* __restrict__ cand, int* __restrict__ sel, int nchunk) {
    const int row = blockIdx.x;
    const int l = threadIdx.x;
    const int ncand = nchunk * 10;   // 500
    const unsigned* cr = cand + (size_t)row * ncand;
    unsigned p[8]; int c[8];
#pragma unroll
    for (int j = 0; j < 8; ++j) {
        const int slot = l * 8 + j;
        if (slot < ncand) {
            const unsigned v = cr[slot];
            p[j] = v;
            c[j] = (slot / 10) * CHUNKC + (2047 - (int)(v & 0x7FFu));
        } else { p[j] = 0u; c[j] = 0x7fffffff; }
    }
    int* out = sel + (size_t)row * NSEL;
    for (int r = 0; r < NSEL; ++r) {
        unsigned bp = 0u; int bc = 0x7fffffff;
#pragma unroll
        for (int j = 0; j < 8; ++j)
            if (p[j] > bp || (p[j] == bp && c[j] < bc)) { bp = p[j]; bc = c[j]; }
#pragma unroll
        for (int m = 1; m < 64; m <<= 1) {
            const unsigned op = __shfl_xor(bp, m);
            const int oc = __shfl_xor(bc, m);
            if (op > bp || (op == bp && oc < bc)) { bp = op; bc = oc; }
        }
        if (l == 0) out[r] = bc;
#pragma unroll
        for (int j = 0; j < 8; ++j)
            if (p[j] == bp && c[j] == bc) { p[j] = 0u; c[j] = 0x7fffffff; }
    }
}

// ---------- kernel 4: exact fp32 rescore of 16 candidates -> final top-5 ----------
__global__ __launch_bounds__(256) void rescore_kernel(
    const float* __restrict__ img, const float* __restrict__ attr,
    const float* __restrict__ inv, const int* __restrict__ sel,
    float* __restrict__ out_scores, int* __restrict__ final_i) {
    __shared__ float s_sc[NSEL];
    const int row = blockIdx.x;
    const int w = threadIdx.x >> 6, l = threadIdx.x & 63;
    const float4* ip = reinterpret_cast<const float4*>(img) + (size_t)row * (FEAT / 4);
    const float4 a0 = ip[l * 2], a1 = ip[l * 2 + 1];
#pragma unroll
    for (int q = 0; q < 4; ++q) {
        const int slot = w * 4 + q;
        const int ci = sel[(size_t)row * NSEL + slot];
        const float4* ap = reinterpret_cast<const float4*>(attr) + (size_t)ci * (FEAT / 4);
        const float4 b0 = ap[l * 2], b1 = ap[l * 2 + 1];
        float d = a0.x * b0.x + a0.y * b0.y + a0.z * b0.z + a0.w * b0.w +
                  a1.x * b1.x + a1.y * b1.y + a1.z * b1.z + a1.w * b1.w;
#pragma unroll
        for (int m = 1; m < 64; m <<= 1) d += __shfl_xor(d, m);
        if (l == 0) s_sc[slot] = d * inv[ci];
    }
    __syncthreads();
    if (threadIdx.x == 0) {
        float ts[TOPK]; int ti[TOPK];
#pragma unroll
        for (int j = 0; j < TOPK; ++j) { ts[j] = -FLT_MAX; ti[j] = 0x7fffffff; }
        for (int e = 0; e < NSEL; ++e) {
            const float sv = s_sc[e];
            const int iv = sel[(size_t)row * NSEL + e];
            if (sv > ts[4] || (sv == ts[4] && iv < ti[4])) {
                ts[4] = sv; ti[4] = iv;
#pragma unroll
                for (int x = 4; x > 0; --x)
                    if (ts[x] > ts[x - 1] || (ts[x] == ts[x - 1] && ti[x] < ti[x - 1])) {
                        const float tf = ts[x]; ts[x] = ts[x - 1]; ts[x - 1] = tf;
                        const int td = ti[x]; ti[x] = ti[x - 1]; ti[x - 1] = td;
                    }
            }
        }
#pragma unroll
        for (int j = 0; j < TOPK; ++j) {
            out_scores[(size_t)row * TOPK + j] = ts[j];
            final_i[(size_t)row * TOPK + j] = ti[j];
        }
    }
}

// ---------- kernel 5: gather normalized winners ----------
__global__ __launch_bounds__(128) void gather_kernel(
    const float* __restrict__ attr, const float* __restrict__ inv,
    const int* __restrict__ final_i, float* __restrict__ out0) {
    const int pair = blockIdx.x;   // b*TOPK + k
    const int fi = final_i[pair];
    const float sc = inv[fi];
    const float4 v =
        reinterpret_cast<const float4*>(attr)[(size_t)fi * (FEAT / 4) + threadIdx.x];
    float4 o;
    o.x = v.x * sc; o.y = v.y * sc; o.z = v.z * sc; o.w = v.w * sc;
    reinterpret_cast<float4*>(out0)[(size_t)pair * (FEAT / 4) + threadIdx.x] = o;
}

extern "C" void kernel_launch(void* const* d_in, const int* in_sizes, int n_in,
                              void* d_out, int out_size, void* d_ws, size_t ws_size,
                              hipStream_t stream) {
    const float* img = (const float*)d_in[0];
    const float* attr = (const float*)d_in[1];
    const int batch = in_sizes[0] / FEAT;    // 4096
    const int nattr = in_sizes[1] / FEAT;    // 64000
    const int nchunk = nattr / CHUNKC;       // 50

    // workspace layout (~78.5 MB, 16B-aligned segments)
    char* ws = (char*)d_ws;
    unsigned short* imgB = (unsigned short*)ws;  ws += (size_t)batch * FEAT * 2;
    unsigned short* attrB = (unsigned short*)ws; ws += (size_t)nattr * FEAT * 2;
    float* inv = (float*)ws;                     ws += (size_t)nattr * 4;
    unsigned* cand = (unsigned*)ws;              ws += (size_t)batch * nchunk * 10 * 4;
    int* sel = (int*)ws;                         ws += (size_t)batch * NSEL * 4;
    int* final_i = (int*)ws;                     ws += (size_t)batch * TOPK * 4;

    float* out0 = (float*)d_out;                             // [batch][5][512]
    float* out_scores = out0 + (size_t)batch * TOPK * FEAT;  // [batch][5]

    convert_kernel<<<nattr / 4, 256, 0, stream>>>(attr, attrB, inv, 1);
    convert_kernel<<<batch / 4, 256, 0, stream>>>(img, imgB, (float*)nullptr, 0);
    dim3 g(batch / BM, nchunk);
    coarse_kernel<<<g, 256, 0, stream>>>(imgB, attrB, cand, nchunk);
    select16_kernel<<<batch, 64, 0, stream>>>(cand, sel, nchunk);
    rescore_kernel<<<batch, 256, 0, stream>>>(img, attr, inv, sel, out_scores, final_i);
    gather_kernel<<<batch * TOPK, 128, 0, stream>>>(attr, inv, final_i, out0);
}

// Round 3
// 463.334 us; speedup vs baseline: 8.4823x; 1.3588x over previous
//
#include <hip/hip_runtime.h>
#include <float.h>

#define FEAT 512
#define TOPK 5
#define NSEL 16
#define ABLK 512                      // attrs per block (2 sub-passes)
#define SUBA 256                      // attrs per sub-pass (LDS A rows)
#define IBLK 64                       // imgs per block
#define BKT 64                        // K per tile
#define NVKT 16                       // 2 subs x 8 K-tiles
#define A_SH (SUBA * BKT)             // 16384 shorts (A region per buffer)
#define BUF_SH ((SUBA + IBLK) * BKT)  // 20480 shorts per buffer

typedef __attribute__((ext_vector_type(8))) short bf16x8;
typedef __attribute__((ext_vector_type(8))) unsigned short ushort8;
typedef __attribute__((ext_vector_type(4))) float f32x4;

__device__ __forceinline__ unsigned short f2bf(float f) {
    unsigned x = __float_as_uint(f);
    x += 0x7FFFu + ((x >> 16) & 1u);  // RNE
    return (unsigned short)(x >> 16);
}

__device__ __forceinline__ void gl_lds16(const void* g, void* lds) {
    __builtin_amdgcn_global_load_lds(
        (const __attribute__((address_space(1))) unsigned int*)g,
        (__attribute__((address_space(3))) unsigned int*)lds, 16, 0, 0);
}

// ---------- kernel 1: (optional) L2-normalize + convert fp32 -> bf16 ----------
__global__ __launch_bounds__(256) void convert_kernel(
    const float* __restrict__ in, unsigned short* __restrict__ outB,
    float* __restrict__ inv, int do_norm) {
    const int w = threadIdx.x >> 6, l = threadIdx.x & 63;
    const int row = blockIdx.x * 4 + w;
    const float4* p = reinterpret_cast<const float4*>(in) + (size_t)row * (FEAT / 4);
    const float4 v0 = p[l * 2], v1 = p[l * 2 + 1];
    float sc = 1.0f;
    if (do_norm) {
        float s = v0.x * v0.x + v0.y * v0.y + v0.z * v0.z + v0.w * v0.w +
                  v1.x * v1.x + v1.y * v1.y + v1.z * v1.z + v1.w * v1.w;
#pragma unroll
        for (int m = 1; m < 64; m <<= 1) s += __shfl_xor(s, m);
        sc = 1.0f / sqrtf(s);
        if (l == 0) inv[row] = sc;
    }
    ushort8 o;
    o[0] = f2bf(v0.x * sc); o[1] = f2bf(v0.y * sc);
    o[2] = f2bf(v0.z * sc); o[3] = f2bf(v0.w * sc);
    o[4] = f2bf(v1.x * sc); o[5] = f2bf(v1.y * sc);
    o[6] = f2bf(v1.z * sc); o[7] = f2bf(v1.w * sc);
    *reinterpret_cast<ushort8*>(outB + (size_t)row * FEAT + l * 8) = o;
}

// packed-u32 top5 merge across lanes (bitonic top-k + 10-CE sort network)
__device__ __forceinline__ void merge5u(unsigned (&s)[TOPK], int mask) {
    unsigned m[TOPK];
#pragma unroll
    for (int j = 0; j < TOPK; ++j) {
        const unsigned o = __shfl_xor(s[TOPK - 1 - j], mask);
        m[j] = o > s[j] ? o : s[j];
    }
#define CEU(a, b) { if (m[b] > m[a]) { unsigned t_ = m[a]; m[a] = m[b]; m[b] = t_; } }
    CEU(0, 1) CEU(1, 2) CEU(2, 3) CEU(3, 4)
    CEU(0, 1) CEU(1, 2) CEU(2, 3)
    CEU(0, 1) CEU(1, 2)
    CEU(0, 1)
#undef CEU
#pragma unroll
    for (int j = 0; j < TOPK; ++j) s[j] = m[j];
}

// ---------- kernel 2: bf16 MFMA coarse scoring, swapped operands ----------
// D = attr x img: lane's C-col = img  ==> per-img top5 is register-local.
// Block: 512 attrs (2 subs x 256) x 64 imgs, 4 waves stacked in M.
// LDS double-buffered (80KB), counted vmcnt(10), XOR granule swizzle.
__global__ __launch_bounds__(256, 2) void coarse_kernel(
    const unsigned short* __restrict__ attrB,
    const unsigned short* __restrict__ imgB,
    unsigned* __restrict__ cand, int nablk, int niblk) {
    __shared__ unsigned short lds[2][BUF_SH];
    const int tid = threadIdx.x;

    // bijective XCD swizzle (gridDim.x % 8 == 0)
    const int cpx = gridDim.x >> 3;
    const int wg = ((int)blockIdx.x & 7) * cpx + ((int)blockIdx.x >> 3);
    const int ablock = wg / niblk;
    const int iblock = wg % niblk;

    const int w = tid >> 6, l = tid & 63;
    const int lrow = l & 15, lq = l >> 4, lx = l & 7;

    // staging: thread covers (row = slot*32 + tid>>3, granule tid&7); source is
    // pre-swizzled so linear gl_lds dest + swizzled ds_read agree (involution).
    const int rsub = tid >> 3;                // 0..31
    const int gsw = (tid & 7) ^ (rsub & 7);   // source granule (8 shorts)
    const unsigned short* asrc0 =
        attrB + (size_t)(ablock * ABLK + rsub) * FEAT + gsw * 8;
    const unsigned short* bsrc0 =
        imgB + (size_t)(iblock * IBLK + rsub) * FEAT + gsw * 8;

    // fragment read offsets (shorts); swz[s] = swizzled granule for kstep s
    const int swz[2] = { ((lq ^ lx) * 8), (((4 + lq) ^ lx) * 8) };
    const int arowbase = (w * 64 + lrow) * BKT;   // + m*16*BKT
    const int browbase = A_SH + lrow * BKT;       // + n*16*BKT

    f32x4 acc[4][4];
#pragma unroll
    for (int m = 0; m < 4; ++m)
#pragma unroll
        for (int n = 0; n < 4; ++n) acc[m][n] = (f32x4){0.f, 0.f, 0.f, 0.f};
    unsigned tops[4][TOPK];
#pragma unroll
    for (int n = 0; n < 4; ++n)
#pragma unroll
        for (int j = 0; j < TOPK; ++j) tops[n][j] = 0u;

#define STAGE(bufi, vkt)                                                      \
    {                                                                         \
        const int sub_ = (vkt) >> 3, kt_ = (vkt) & 7;                         \
        const unsigned short* as_ = asrc0 + sub_ * SUBA * FEAT + kt_ * BKT;   \
        const unsigned short* bs_ = bsrc0 + kt_ * BKT;                        \
        unsigned short* d_ = &lds[bufi][tid * 8];                             \
        _Pragma("unroll")                                                     \
        for (int i_ = 0; i_ < 8; ++i_)                                        \
            gl_lds16(as_ + (size_t)i_ * 32 * FEAT, d_ + i_ * 2048);           \
        _Pragma("unroll")                                                     \
        for (int j_ = 0; j_ < 2; ++j_)                                        \
            gl_lds16(bs_ + (size_t)j_ * 32 * FEAT, d_ + A_SH + j_ * 2048);    \
    }

#define COMPUTE(bufi)                                                         \
    {                                                                         \
        _Pragma("unroll")                                                     \
        for (int s_ = 0; s_ < 2; ++s_) {                                      \
            bf16x8 aF[4], bF[4];                                              \
            _Pragma("unroll")                                                 \
            for (int m_ = 0; m_ < 4; ++m_)                                    \
                aF[m_] = *reinterpret_cast<const bf16x8*>(                    \
                    &lds[bufi][arowbase + m_ * 16 * BKT + swz[s_]]);          \
            _Pragma("unroll")                                                 \
            for (int n_ = 0; n_ < 4; ++n_)                                    \
                bF[n_] = *reinterpret_cast<const bf16x8*>(                    \
                    &lds[bufi][browbase + n_ * 16 * BKT + swz[s_]]);          \
            __builtin_amdgcn_s_setprio(1);                                    \
            _Pragma("unroll")                                                 \
            for (int m_ = 0; m_ < 4; ++m_)                                    \
                _Pragma("unroll")                                             \
                for (int n_ = 0; n_ < 4; ++n_)                                \
                    acc[m_][n_] = __builtin_amdgcn_mfma_f32_16x16x32_bf16(    \
                        aF[m_], bF[n_], acc[m_][n_], 0, 0, 0);                \
            __builtin_amdgcn_s_setprio(0);                                    \
        }                                                                     \
    }

    STAGE(0, 0);
#pragma unroll 1
    for (int vkt = 0; vkt < NVKT; ++vkt) {
        const int cur = vkt & 1;
        if (vkt < NVKT - 1) STAGE(cur ^ 1, vkt + 1);
        __builtin_amdgcn_sched_barrier(0);
        if (vkt < NVKT - 1) {
            asm volatile("s_waitcnt vmcnt(10)" ::: "memory");
        } else {
            asm volatile("s_waitcnt vmcnt(0)" ::: "memory");
        }
        __builtin_amdgcn_s_barrier();
        __builtin_amdgcn_sched_barrier(0);
        COMPUTE(cur);
        __builtin_amdgcn_sched_barrier(0);
        __builtin_amdgcn_s_barrier();
        __builtin_amdgcn_sched_barrier(0);
        if ((vkt & 7) == 7) {
            // fold acc into per-lane packed top5 (register-only), reset acc
            const int sub_ = vkt >> 3;
#pragma unroll
            for (int n = 0; n < 4; ++n)
#pragma unroll
                for (int m = 0; m < 4; ++m)
#pragma unroll
                    for (int r = 0; r < 4; ++r) {
                        unsigned u = __float_as_uint(acc[m][n][r]);
                        u = ((int)u < 0) ? ~u : (u | 0x80000000u);
                        const unsigned idx =
                            (unsigned)(sub_ * SUBA + w * 64 + m * 16 + lq * 4 + r);
                        const unsigned p = (u & 0xFFFFF800u) | (2047u - idx);
                        if (p > tops[n][TOPK - 1]) {
                            tops[n][TOPK - 1] = p;
#pragma unroll
                            for (int x = TOPK - 1; x > 0; --x)
                                if (tops[n][x] > tops[n][x - 1]) {
                                    const unsigned t_ = tops[n][x];
                                    tops[n][x] = tops[n][x - 1];
                                    tops[n][x - 1] = t_;
                                }
                        }
                        acc[m][n][r] = 0.f;
                    }
        }
    }
#undef STAGE
#undef COMPUTE

    // intra-wave merge: lanes l, l^16, l^32, l^48 share img = n*16 + (l&15)
#pragma unroll
    for (int n = 0; n < 4; ++n) { merge5u(tops[n], 16); merge5u(tops[n], 32); }

    __syncthreads();  // all K-loop LDS traffic done; reuse as scratch
    unsigned* scratch = (unsigned*)&lds[0][0];  // [4 waves][64 imgs][5]
    if (l < 16) {
#pragma unroll
        for (int n = 0; n < 4; ++n)
#pragma unroll
            for (int j = 0; j < TOPK; ++j)
                scratch[(w * 64 + n * 16 + l) * TOPK + j] = tops[n][j];
    }
    __syncthreads();
    if (tid < IBLK) {
        unsigned best[TOPK] = {0u, 0u, 0u, 0u, 0u};
#pragma unroll
        for (int w2 = 0; w2 < 4; ++w2)
#pragma unroll
            for (int j = 0; j < TOPK; ++j) {
                const unsigned p = scratch[(w2 * 64 + tid) * TOPK + j];
                if (p > best[TOPK - 1]) {
                    best[TOPK - 1] = p;
#pragma unroll
                    for (int x = TOPK - 1; x > 0; --x)
                        if (best[x] > best[x - 1]) {
                            const unsigned t_ = best[x];
                            best[x] = best[x - 1]; best[x - 1] = t_;
                        }
                }
            }
        const size_t base = ((size_t)(iblock * IBLK + tid) * nablk + ablock) * TOPK;
#pragma unroll
        for (int j = 0; j < TOPK; ++j) cand[base + j] = best[j];
    }
}

// ---------- kernel 3: per-img merge of nablk*5 packed candidates -> top-16 ----------
__global__ __launch_bounds__(64) void select16_kernel(
    const unsigned* __restrict__ cand, int* __restrict__ sel, int nablk) {
    const int row = blockIdx.x;
    const int l = threadIdx.x;
    const int ncand = nablk * TOPK;  // 625
    const unsigned* cr = cand + (size_t)row * ncand;
    unsigned p[10]; int c[10];
#pragma unroll
    for (int j = 0; j < 10; ++j) {
        const int slot = l * 10 + j;
        if (slot < ncand) {
            const unsigned v = cr[slot];
            p[j] = v;
            c[j] = (slot / TOPK) * ABLK + (2047 - (int)(v & 0x7FFu));
        } else { p[j] = 0u; c[j] = 0x7fffffff; }
    }
    int* out = sel + (size_t)row * NSEL;
    for (int r = 0; r < NSEL; ++r) {
        unsigned bp = 0u; int bc = 0x7fffffff;
#pragma unroll
        for (int j = 0; j < 10; ++j)
            if (p[j] > bp || (p[j] == bp && c[j] < bc)) { bp = p[j]; bc = c[j]; }
#pragma unroll
        for (int m = 1; m < 64; m <<= 1) {
            const unsigned op = __shfl_xor(bp, m);
            const int oc = __shfl_xor(bc, m);
            if (op > bp || (op == bp && oc < bc)) { bp = op; bc = oc; }
        }
        if (l == 0) out[r] = bc;
#pragma unroll
        for (int j = 0; j < 10; ++j)
            if (p[j] == bp && c[j] == bc) { p[j] = 0u; c[j] = 0x7fffffff; }
    }
}

// ---------- kernel 4: exact fp32 rescore of 16 candidates -> final top-5 ----------
__global__ __launch_bounds__(256) void rescore_kernel(
    const float* __restrict__ img, const float* __restrict__ attr,
    const float* __restrict__ inv, const int* __restrict__ sel,
    float* __restrict__ out_scores, int* __restrict__ final_i) {
    __shared__ float s_sc[NSEL];
    const int row = blockIdx.x;
    const int w = threadIdx.x >> 6, l = threadIdx.x & 63;
    const float4* ip = reinterpret_cast<const float4*>(img) + (size_t)row * (FEAT / 4);
    const float4 a0 = ip[l * 2], a1 = ip[l * 2 + 1];
#pragma unroll
    for (int q = 0; q < 4; ++q) {
        const int slot = w * 4 + q;
        const int ci = sel[(size_t)row * NSEL + slot];
        const float4* ap = reinterpret_cast<const float4*>(attr) + (size_t)ci * (FEAT / 4);
        const float4 b0 = ap[l * 2], b1 = ap[l * 2 + 1];
        float d = a0.x * b0.x + a0.y * b0.y + a0.z * b0.z + a0.w * b0.w +
                  a1.x * b1.x + a1.y * b1.y + a1.z * b1.z + a1.w * b1.w;
#pragma unroll
        for (int m = 1; m < 64; m <<= 1) d += __shfl_xor(d, m);
        if (l == 0) s_sc[slot] = d * inv[ci];
    }
    __syncthreads();
    if (threadIdx.x == 0) {
        float ts[TOPK]; int ti[TOPK];
#pragma unroll
        for (int j = 0; j < TOPK; ++j) { ts[j] = -FLT_MAX; ti[j] = 0x7fffffff; }
        for (int e = 0; e < NSEL; ++e) {
            const float sv = s_sc[e];
            const int iv = sel[(size_t)row * NSEL + e];
            if (sv > ts[4] || (sv == ts[4] && iv < ti[4])) {
                ts[4] = sv; ti[4] = iv;
#pragma unroll
                for (int x = 4; x > 0; --x)
                    if (ts[x] > ts[x - 1] || (ts[x] == ts[x - 1] && ti[x] < ti[x - 1])) {
                        const float tf = ts[x]; ts[x] = ts[x - 1]; ts[x - 1] = tf;
                        const int td = ti[x]; ti[x] = ti[x - 1]; ti[x - 1] = td;
                    }
            }
        }
#pragma unroll
        for (int j = 0; j < TOPK; ++j) {
            out_scores[(size_t)row * TOPK + j] = ts[j];
            final_i[(size_t)row * TOPK + j] = ti[j];
        }
    }
}

// ---------- kernel 5: gather normalized winners ----------
__global__ __launch_bounds__(128) void gather_kernel(
    const float* __restrict__ attr, const float* __restrict__ inv,
    const int* __restrict__ final_i, float* __restrict__ out0) {
    const int pair = blockIdx.x;  // b*TOPK + k
    const int fi = final_i[pair];
    const float sc = inv[fi];
    const float4 v =
        reinterpret_cast<const float4*>(attr)[(size_t)fi * (FEAT / 4) + threadIdx.x];
    float4 o;
    o.x = v.x * sc; o.y = v.y * sc; o.z = v.z * sc; o.w = v.w * sc;
    reinterpret_cast<float4*>(out0)[(size_t)pair * (FEAT / 4) + threadIdx.x] = o;
}

extern "C" void kernel_launch(void* const* d_in, const int* in_sizes, int n_in,
                              void* d_out, int out_size, void* d_ws, size_t ws_size,
                              hipStream_t stream) {
    const float* img = (const float*)d_in[0];
    const float* attr = (const float*)d_in[1];
    const int batch = in_sizes[0] / FEAT;  // 4096
    const int nattr = in_sizes[1] / FEAT;  // 64000
    const int nablk = nattr / ABLK;        // 125
    const int niblk = batch / IBLK;        // 64

    // workspace layout (~80.6 MB, 16B-aligned segments)
    char* ws = (char*)d_ws;
    unsigned short* imgB = (unsigned short*)ws;  ws += (size_t)batch * FEAT * 2;
    unsigned short* attrB = (unsigned short*)ws; ws += (size_t)nattr * FEAT * 2;
    float* inv = (float*)ws;                     ws += (size_t)nattr * 4;
    unsigned* cand = (unsigned*)ws;              ws += (size_t)batch * nablk * TOPK * 4;
    int* sel = (int*)ws;                         ws += (size_t)batch * NSEL * 4;
    int* final_i = (int*)ws;                     ws += (size_t)batch * TOPK * 4;

    float* out0 = (float*)d_out;                             // [batch][5][512]
    float* out_scores = out0 + (size_t)batch * TOPK * FEAT;  // [batch][5]

    convert_kernel<<<nattr / 4, 256, 0, stream>>>(attr, attrB, inv, 1);
    convert_kernel<<<batch / 4, 256, 0, stream>>>(img, imgB, (float*)nullptr, 0);
    coarse_kernel<<<nablk * niblk, 256, 0, stream>>>(attrB, imgB, cand, nablk, niblk);
    select16_kernel<<<batch, 64, 0, stream>>>(cand, sel, nablk);
    rescore_kernel<<<batch, 256, 0, stream>>>(img, attr, inv, sel, out_scores, final_i);
    gather_kernel<<<batch * TOPK, 128, 0, stream>>>(attr, inv, final_i, out0);
}

// Round 4
// 397.894 us; speedup vs baseline: 9.8774x; 1.1645x over previous
//
#include <hip/hip_runtime.h>
#include <float.h>

#define FEAT 512
#define TOPK 5
#define NSEL 16
#define ABLK 512                       // attrs per block
#define IBLK 64                        // imgs per block
#define BKT 64                         // K elems (bytes, i8) per tile
#define NKT (FEAT / BKT)               // 8
#define A_BYTES (ABLK * BKT)           // 32768
#define B_BYTES (IBLK * BKT)           // 4096
#define BUF_BYTES (A_BYTES + B_BYTES)  // 36864

typedef __attribute__((ext_vector_type(4))) int i32x4;

__device__ __forceinline__ void gl_lds16(const void* g, void* lds) {
    __builtin_amdgcn_global_load_lds(
        (const __attribute__((address_space(1))) unsigned int*)g,
        (__attribute__((address_space(3))) unsigned int*)lds, 16, 0, 0);
}

// ---------- kernel 1a: attr -> int8 (per-row scale), plus inv-norm & score scale ----
__global__ __launch_bounds__(256) void quant_attr(
    const float* __restrict__ in, signed char* __restrict__ q,
    float* __restrict__ sattr, float* __restrict__ inv) {
    const int w = threadIdx.x >> 6, l = threadIdx.x & 63;
    const int row = blockIdx.x * 4 + w;
    const float4* p = reinterpret_cast<const float4*>(in) + (size_t)row * (FEAT / 4);
    const float4 v0 = p[l * 2], v1 = p[l * 2 + 1];
    float ss = v0.x * v0.x + v0.y * v0.y + v0.z * v0.z + v0.w * v0.w +
               v1.x * v1.x + v1.y * v1.y + v1.z * v1.z + v1.w * v1.w;
    float mx = fmaxf(fmaxf(fmaxf(fabsf(v0.x), fabsf(v0.y)), fmaxf(fabsf(v0.z), fabsf(v0.w))),
                     fmaxf(fmaxf(fabsf(v1.x), fabsf(v1.y)), fmaxf(fabsf(v1.z), fabsf(v1.w))));
#pragma unroll
    for (int m = 1; m < 64; m <<= 1) {
        ss += __shfl_xor(ss, m);
        mx = fmaxf(mx, __shfl_xor(mx, m));
    }
    mx = fmaxf(mx, 1e-20f);
    const float iv = 1.0f / sqrtf(ss);
    const float qs = 127.0f / mx;
    const int q0 = __float2int_rn(v0.x * qs), q1 = __float2int_rn(v0.y * qs);
    const int q2 = __float2int_rn(v0.z * qs), q3 = __float2int_rn(v0.w * qs);
    const int q4 = __float2int_rn(v1.x * qs), q5 = __float2int_rn(v1.y * qs);
    const int q6 = __float2int_rn(v1.z * qs), q7 = __float2int_rn(v1.w * qs);
    int2 st;
    st.x = (q0 & 255) | ((q1 & 255) << 8) | ((q2 & 255) << 16) | ((unsigned)(q3 & 255) << 24);
    st.y = (q4 & 255) | ((q5 & 255) << 8) | ((q6 & 255) << 16) | ((unsigned)(q7 & 255) << 24);
    *reinterpret_cast<int2*>(q + (size_t)row * FEAT + l * 8) = st;
    if (l == 0) {
        inv[row] = iv;
        sattr[row] = mx * iv * (1.0f / 127.0f);  // score = idot * sattr (img scale cancels)
    }
}

// ---------- kernel 1b: img -> int8 (per-row scale, scale not needed for ranking) ----
__global__ __launch_bounds__(256) void quant_img(
    const float* __restrict__ in, signed char* __restrict__ q) {
    const int w = threadIdx.x >> 6, l = threadIdx.x & 63;
    const int row = blockIdx.x * 4 + w;
    const float4* p = reinterpret_cast<const float4*>(in) + (size_t)row * (FEAT / 4);
    const float4 v0 = p[l * 2], v1 = p[l * 2 + 1];
    float mx = fmaxf(fmaxf(fmaxf(fabsf(v0.x), fabsf(v0.y)), fmaxf(fabsf(v0.z), fabsf(v0.w))),
                     fmaxf(fmaxf(fabsf(v1.x), fabsf(v1.y)), fmaxf(fabsf(v1.z), fabsf(v1.w))));
#pragma unroll
    for (int m = 1; m < 64; m <<= 1) mx = fmaxf(mx, __shfl_xor(mx, m));
    mx = fmaxf(mx, 1e-20f);
    const float qs = 127.0f / mx;
    const int q0 = __float2int_rn(v0.x * qs), q1 = __float2int_rn(v0.y * qs);
    const int q2 = __float2int_rn(v0.z * qs), q3 = __float2int_rn(v0.w * qs);
    const int q4 = __float2int_rn(v1.x * qs), q5 = __float2int_rn(v1.y * qs);
    const int q6 = __float2int_rn(v1.z * qs), q7 = __float2int_rn(v1.w * qs);
    int2 st;
    st.x = (q0 & 255) | ((q1 & 255) << 8) | ((q2 & 255) << 16) | ((unsigned)(q3 & 255) << 24);
    st.y = (q4 & 255) | ((q5 & 255) << 8) | ((q6 & 255) << 16) | ((unsigned)(q7 & 255) << 24);
    *reinterpret_cast<int2*>(q + (size_t)row * FEAT + l * 8) = st;
}

// packed-u32 top5 merge across lanes (bitonic top-k + 10-CE sort network)
__device__ __forceinline__ void merge5u(unsigned (&s)[TOPK], int mask) {
    unsigned m[TOPK];
#pragma unroll
    for (int j = 0; j < TOPK; ++j) {
        const unsigned o = __shfl_xor(s[TOPK - 1 - j], mask);
        m[j] = o > s[j] ? o : s[j];
    }
#define CEU(a, b) { if (m[b] > m[a]) { unsigned t_ = m[a]; m[a] = m[b]; m[b] = t_; } }
    CEU(0, 1) CEU(1, 2) CEU(2, 3) CEU(3, 4)
    CEU(0, 1) CEU(1, 2) CEU(2, 3)
    CEU(0, 1) CEU(1, 2)
    CEU(0, 1)
#undef CEU
#pragma unroll
    for (int j = 0; j < TOPK; ++j) s[j] = m[j];
}

// ---------- kernel 2: i8 MFMA coarse scoring (attr x img), reg-local top-5 ----------
// Block: 512 attrs x 64 imgs, 4 waves stacked in M (wave tile 128x64).
// acc[8][4] i32x4 (128 VGPR). LDS dbuf 72KB + 2KB scales; counted vmcnt(9).
__global__ __launch_bounds__(256, 2) void coarse_kernel(
    const signed char* __restrict__ attrQ, const signed char* __restrict__ imgQ,
    const float* __restrict__ sattr, unsigned* __restrict__ cand,
    int nablk, int niblk) {
    __shared__ char lds[2][BUF_BYTES];
    __shared__ float ssc[ABLK];
    const int tid = threadIdx.x;

    // bijective XCD swizzle (gridDim.x % 8 == 0); iblock fastest within XCD
    const int cpx = gridDim.x >> 3;
    const int wg = ((int)blockIdx.x & 7) * cpx + ((int)blockIdx.x >> 3);
    const int ablock = wg / niblk;
    const int iblock = wg % niblk;

    const int w = tid >> 6, l = tid & 63;
    const int lrow = l & 15, lg = l >> 4;

    // ---- staging geometry (pre-swizzled source; linear gl_lds dest) ----
    // A: thread covers slots tid + i*256 (i<8); row = slot>>2, granule = slot&3.
    // sw(row) = (row ^ (row>>2)) & 3 is invariant across i (row step 64).
    const int arow0 = tid >> 2, ag = tid & 3;
    const int asw = (arow0 ^ (arow0 >> 2)) & 3;
    const signed char* asrc0 =
        attrQ + (size_t)(ablock * ABLK + arow0) * FEAT + ((ag ^ asw) << 4);
    // B: thread covers slot tid; row = tid>>2 (0..63), granule = tid&3.
    const int brow = tid >> 2, bg = tid & 3;
    const int bsw = (brow ^ (brow >> 2)) & 3;
    const signed char* bsrc0 =
        imgQ + (size_t)(iblock * IBLK + brow) * FEAT + ((bg ^ bsw) << 4);

    // ---- fragment read offsets (swizzled) ----
    int a_off[8], b_off[4];
#pragma unroll
    for (int m = 0; m < 8; ++m) {
        const int r = w * 128 + m * 16 + lrow;
        a_off[m] = r * BKT + ((lg ^ ((r ^ (r >> 2)) & 3)) << 4);
    }
#pragma unroll
    for (int n = 0; n < 4; ++n) {
        const int r = n * 16 + lrow;
        b_off[n] = A_BYTES + r * BKT + ((lg ^ ((r ^ (r >> 2)) & 3)) << 4);
    }

    // stage per-attr score scales (512 floats) via gl_lds
    if (tid < 128) gl_lds16(sattr + (size_t)ablock * ABLK + tid * 4, &ssc[tid * 4]);

    i32x4 acc[8][4];
#pragma unroll
    for (int m = 0; m < 8; ++m)
#pragma unroll
        for (int n = 0; n < 4; ++n) acc[m][n] = (i32x4){0, 0, 0, 0};

#define STAGE(bufi, kt)                                                     \
    {                                                                       \
        const signed char* as_ = asrc0 + (kt) * BKT;                        \
        const signed char* bs_ = bsrc0 + (kt) * BKT;                        \
        char* d_ = &lds[bufi][tid * 16];                                    \
        char* dB_ = &lds[bufi][A_BYTES + tid * 16];                         \
        _Pragma("unroll")                                                   \
        for (int i_ = 0; i_ < 8; ++i_)                                      \
            gl_lds16(as_ + (size_t)i_ * 64 * FEAT, d_ + i_ * 4096);         \
        gl_lds16(bs_, dB_);                                                 \
    }

#define COMPUTE(bufi)                                                       \
    {                                                                       \
        i32x4 aF[8], bF[4];                                                 \
        _Pragma("unroll")                                                   \
        for (int m_ = 0; m_ < 8; ++m_)                                      \
            aF[m_] = *reinterpret_cast<const i32x4*>(&lds[bufi][a_off[m_]]);\
        _Pragma("unroll")                                                   \
        for (int n_ = 0; n_ < 4; ++n_)                                      \
            bF[n_] = *reinterpret_cast<const i32x4*>(&lds[bufi][b_off[n_]]);\
        __builtin_amdgcn_s_setprio(1);                                      \
        _Pragma("unroll")                                                   \
        for (int m_ = 0; m_ < 8; ++m_)                                      \
            _Pragma("unroll")                                               \
            for (int n_ = 0; n_ < 4; ++n_)                                  \
                acc[m_][n_] = __builtin_amdgcn_mfma_i32_16x16x64_i8(        \
                    aF[m_], bF[n_], acc[m_][n_], 0, 0, 0);                  \
        __builtin_amdgcn_s_setprio(0);                                      \
    }

    STAGE(0, 0);
#pragma unroll 1
    for (int kt = 0; kt < NKT; ++kt) {
        const int cur = kt & 1;
        if (kt < NKT - 1) STAGE(cur ^ 1, kt + 1);
        __builtin_amdgcn_sched_barrier(0);
        if (kt < NKT - 1) {
            asm volatile("s_waitcnt vmcnt(9)" ::: "memory");
        } else {
            asm volatile("s_waitcnt vmcnt(0)" ::: "memory");
        }
        __builtin_amdgcn_s_barrier();
        __builtin_amdgcn_sched_barrier(0);
        COMPUTE(cur);
        __builtin_amdgcn_sched_barrier(0);
        __builtin_amdgcn_s_barrier();
        __builtin_amdgcn_sched_barrier(0);
    }
#undef STAGE
#undef COMPUTE

    // ---- fold acc -> packed per-lane top5 per n-group (register-local) ----
    unsigned tops[4][TOPK];
#pragma unroll
    for (int n = 0; n < 4; ++n)
#pragma unroll
        for (int j = 0; j < TOPK; ++j) tops[n][j] = 0u;

#pragma unroll
    for (int m = 0; m < 8; ++m)
#pragma unroll
        for (int r = 0; r < 4; ++r) {
            const int rowl = w * 128 + m * 16 + lg * 4 + r;  // local attr 0..511
            const float sc = ssc[rowl];
#pragma unroll
            for (int n = 0; n < 4; ++n) {
                const float sf = (float)acc[m][n][r] * sc;
                unsigned u = __float_as_uint(sf);
                u = ((int)u < 0) ? ~u : (u | 0x80000000u);
                const unsigned pkd = (u & 0xFFFFF800u) | (2047u - (unsigned)rowl);
                if (pkd > tops[n][TOPK - 1]) {
                    tops[n][TOPK - 1] = pkd;
#pragma unroll
                    for (int x = TOPK - 1; x > 0; --x)
                        if (tops[n][x] > tops[n][x - 1]) {
                            const unsigned t_ = tops[n][x];
                            tops[n][x] = tops[n][x - 1];
                            tops[n][x - 1] = t_;
                        }
                }
            }
        }

    // intra-wave merge: lanes l, l^16, l^32, l^48 share img col = n*16 + (l&15)
#pragma unroll
    for (int n = 0; n < 4; ++n) { merge5u(tops[n], 16); merge5u(tops[n], 32); }

    __syncthreads();  // K-loop LDS idle; reuse buffer 0 as scratch
    unsigned* scratch = (unsigned*)&lds[0][0];  // [4 waves][64 imgs][5]
    if (l < 16) {
#pragma unroll
        for (int n = 0; n < 4; ++n)
#pragma unroll
            for (int j = 0; j < TOPK; ++j)
                scratch[(w * 64 + n * 16 + l) * TOPK + j] = tops[n][j];
    }
    __syncthreads();
    if (tid < IBLK) {
        unsigned best[TOPK] = {0u, 0u, 0u, 0u, 0u};
#pragma unroll
        for (int w2 = 0; w2 < 4; ++w2)
#pragma unroll
            for (int j = 0; j < TOPK; ++j) {
                const unsigned pkd = scratch[(w2 * 64 + tid) * TOPK + j];
                if (pkd > best[TOPK - 1]) {
                    best[TOPK - 1] = pkd;
#pragma unroll
                    for (int x = TOPK - 1; x > 0; --x)
                        if (best[x] > best[x - 1]) {
                            const unsigned t_ = best[x];
                            best[x] = best[x - 1]; best[x - 1] = t_;
                        }
                }
            }
        const size_t base = ((size_t)(iblock * IBLK + tid) * nablk + ablock) * TOPK;
#pragma unroll
        for (int j = 0; j < TOPK; ++j) cand[base + j] = best[j];
    }
}

// ---------- kernel 3: per-img merge of nablk*5 packed candidates -> top-16 ----------
__global__ __launch_bounds__(64) void select16_kernel(
    const unsigned* __restrict__ cand, int* __restrict__ sel, int nablk) {
    const int row = blockIdx.x;
    const int l = threadIdx.x;
    const int ncand = nablk * TOPK;  // 625
    const unsigned* cr = cand + (size_t)row * ncand;
    unsigned p[10]; int c[10];
#pragma unroll
    for (int j = 0; j < 10; ++j) {
        const int slot = l * 10 + j;
        if (slot < ncand) {
            const unsigned v = cr[slot];
            p[j] = v;
            c[j] = (slot / TOPK) * ABLK + (2047 - (int)(v & 0x7FFu));
        } else { p[j] = 0u; c[j] = 0x7fffffff; }
    }
    int* out = sel + (size_t)row * NSEL;
    for (int r = 0; r < NSEL; ++r) {
        unsigned bp = 0u; int bc = 0x7fffffff;
#pragma unroll
        for (int j = 0; j < 10; ++j)
            if (p[j] > bp || (p[j] == bp && c[j] < bc)) { bp = p[j]; bc = c[j]; }
#pragma unroll
        for (int m = 1; m < 64; m <<= 1) {
            const unsigned op = __shfl_xor(bp, m);
            const int oc = __shfl_xor(bc, m);
            if (op > bp || (op == bp && oc < bc)) { bp = op; bc = oc; }
        }
        if (l == 0) out[r] = bc;
#pragma unroll
        for (int j = 0; j < 10; ++j)
            if (p[j] == bp && c[j] == bc) { p[j] = 0u; c[j] = 0x7fffffff; }
    }
}

// ---------- kernel 4: exact fp32 rescore of 16 candidates -> final top-5 ----------
__global__ __launch_bounds__(256) void rescore_kernel(
    const float* __restrict__ img, const float* __restrict__ attr,
    const float* __restrict__ inv, const int* __restrict__ sel,
    float* __restrict__ out_scores, int* __restrict__ final_i) {
    __shared__ float s_sc[NSEL];
    const int row = blockIdx.x;
    const int w = threadIdx.x >> 6, l = threadIdx.x & 63;
    const float4* ip = reinterpret_cast<const float4*>(img) + (size_t)row * (FEAT / 4);
    const float4 a0 = ip[l * 2], a1 = ip[l * 2 + 1];
#pragma unroll
    for (int q = 0; q < 4; ++q) {
        const int slot = w * 4 + q;
        const int ci = sel[(size_t)row * NSEL + slot];
        const float4* ap = reinterpret_cast<const float4*>(attr) + (size_t)ci * (FEAT / 4);
        const float4 b0 = ap[l * 2], b1 = ap[l * 2 + 1];
        float d = a0.x * b0.x + a0.y * b0.y + a0.z * b0.z + a0.w * b0.w +
                  a1.x * b1.x + a1.y * b1.y + a1.z * b1.z + a1.w * b1.w;
#pragma unroll
        for (int m = 1; m < 64; m <<= 1) d += __shfl_xor(d, m);
        if (l == 0) s_sc[slot] = d * inv[ci];
    }
    __syncthreads();
    if (threadIdx.x == 0) {
        float ts[TOPK]; int ti[TOPK];
#pragma unroll
        for (int j = 0; j < TOPK; ++j) { ts[j] = -FLT_MAX; ti[j] = 0x7fffffff; }
        for (int e = 0; e < NSEL; ++e) {
            const float sv = s_sc[e];
            const int iv = sel[(size_t)row * NSEL + e];
            if (sv > ts[4] || (sv == ts[4] && iv < ti[4])) {
                ts[4] = sv; ti[4] = iv;
#pragma unroll
                for (int x = 4; x > 0; --x)
                    if (ts[x] > ts[x - 1] || (ts[x] == ts[x - 1] && ti[x] < ti[x - 1])) {
                        const float tf = ts[x]; ts[x] = ts[x - 1]; ts[x - 1] = tf;
                        const int td = ti[x]; ti[x] = ti[x - 1]; ti[x - 1] = td;
                    }
            }
        }
#pragma unroll
        for (int j = 0; j < TOPK; ++j) {
            out_scores[(size_t)row * TOPK + j] = ts[j];
            final_i[(size_t)row * TOPK + j] = ti[j];
        }
    }
}

// ---------- kernel 5: gather normalized winners ----------
__global__ __launch_bounds__(128) void gather_kernel(
    const float* __restrict__ attr, const float* __restrict__ inv,
    const int* __restrict__ final_i, float* __restrict__ out0) {
    const int pair = blockIdx.x;  // b*TOPK + k
    const int fi = final_i[pair];
    const float sc = inv[fi];
    const float4 v =
        reinterpret_cast<const float4*>(attr)[(size_t)fi * (FEAT / 4) + threadIdx.x];
    float4 o;
    o.x = v.x * sc; o.y = v.y * sc; o.z = v.z * sc; o.w = v.w * sc;
    reinterpret_cast<float4*>(out0)[(size_t)pair * (FEAT / 4) + threadIdx.x] = o;
}

extern "C" void kernel_launch(void* const* d_in, const int* in_sizes, int n_in,
                              void* d_out, int out_size, void* d_ws, size_t ws_size,
                              hipStream_t stream) {
    const float* img = (const float*)d_in[0];
    const float* attr = (const float*)d_in[1];
    const int batch = in_sizes[0] / FEAT;  // 4096
    const int nattr = in_sizes[1] / FEAT;  // 64000
    const int nablk = nattr / ABLK;        // 125
    const int niblk = batch / IBLK;        // 64

    // workspace layout (~45 MB, 16B-aligned segments)
    char* ws = (char*)d_ws;
    signed char* attrQ = (signed char*)ws; ws += (size_t)nattr * FEAT;
    signed char* imgQ = (signed char*)ws;  ws += (size_t)batch * FEAT;
    float* sattr = (float*)ws;             ws += (size_t)nattr * 4;
    float* inv = (float*)ws;               ws += (size_t)nattr * 4;
    unsigned* cand = (unsigned*)ws;        ws += (size_t)batch * nablk * TOPK * 4;
    int* sel = (int*)ws;                   ws += (size_t)batch * NSEL * 4;
    int* final_i = (int*)ws;               ws += (size_t)batch * TOPK * 4;

    float* out0 = (float*)d_out;                             // [batch][5][512]
    float* out_scores = out0 + (size_t)batch * TOPK * FEAT;  // [batch][5]

    quant_attr<<<nattr / 4, 256, 0, stream>>>(attr, attrQ, sattr, inv);
    quant_img<<<batch / 4, 256, 0, stream>>>(img, imgQ);
    coarse_kernel<<<nablk * niblk, 256, 0, stream>>>(attrQ, imgQ, sattr, cand,
                                                     nablk, niblk);
    select16_kernel<<<batch, 64, 0, stream>>>(cand, sel, nablk);
    rescore_kernel<<<batch, 256, 0, stream>>>(img, attr, inv, sel, out_scores, final_i);
    gather_kernel<<<batch * TOPK, 128, 0, stream>>>(attr, inv, final_i, out0);
}